// Round 7
// baseline (367.545 us; speedup 1.0000x reference)
//
#include <hip/hip_runtime.h>
#include <hip/hip_bf16.h>

// Cabasc: B=64, S=512, Ta=8, D=768
// Round 9: gemm K-loop restored to the twice-measured 63.5us structure
//          (__syncthreads 2-phase, prefetch issued before compute; NO raw
//          barriers / counted vmcnt — that structure measured 82us twice).
//          vs_mprime & vts: 16B (uint4) mp stores/loads, 8 bf16 per lane.
//          Keep: XCD swizzle, prep+transpose fusion, softmax->vts fusion,
//          b-fastest k_ctx/k_final1 grids.

#define NB 64
#define NS 512
#define ND 768
#define NTA 8

typedef __attribute__((ext_vector_type(8))) __bf16 bf16x8;
typedef __attribute__((ext_vector_type(4))) float f32x4;

// ---- workspace layout (bytes) ----
#define OFF_SCORES 0u           // NB*NS f32   = 131072
#define OFF_VS 131072u          // NB*ND f32   = 196608
#define OFF_VTS 327680u         // NB*ND f32
#define OFF_CTX 524288u         // NB*ND f32   (accumulated via atomics)
#define OFF_U 720896u           // NB*ND f32   (pre-tanh v_ms accumulator)
#define ZERO_BYTES 917504u      // [0, 917504) zero-initialized each launch
#define OFF_VA 917504u          // NB*ND f32
#define OFF_LENS 1114112u       // mlenf[64] | inv_mlen[64] | inv_alen[64]
#define OFF_W1MT 1115136u       // ND*ND bf16 = 1179648
#define OFF_MP 2294784u         // NB*NS*ND bf16 = 50331648 (total ~52.6 MB)

__device__ __forceinline__ float fast_tanh(float x) {
  x = fminf(fmaxf(x, -15.f), 15.f);
  float t = __expf(2.f * x);
  return __fdividef(t - 1.f, t + 1.f);
}

__device__ __forceinline__ unsigned bfpack2(float a, float b) {
  unsigned ua = __float_as_uint(a), ub = __float_as_uint(b);
  ua = (ua + 0x7FFFu + ((ua >> 16) & 1u)) >> 16;
  ub = (ub + 0x7FFFu + ((ub >> 16) & 1u)) >> 16;
  return ua | (ub << 16);
}

__device__ __forceinline__ unsigned short bf16b(float f) {
  unsigned u = __float_as_uint(f);
  u = (u + 0x7FFFu + ((u >> 16) & 1u)) >> 16;
  return (unsigned short)u;
}

__device__ __forceinline__ void async_copy16(const void* g, void* l) {
  __builtin_amdgcn_global_load_lds(
      (const __attribute__((address_space(1))) void*)g,
      (__attribute__((address_space(3))) void*)l, 16, 0, 0);
}

// ---------- fused: W1_m transpose (blocks 0..575) + lens/v_a prep (blocks 576..639) ----------
__global__ __launch_bounds__(256) void k_prep_tr(const int* __restrict__ ids,
                                                 const int* __restrict__ tids,
                                                 const float* __restrict__ aspect,
                                                 const float* __restrict__ W1,
                                                 float* __restrict__ v_a,
                                                 float* __restrict__ lens,
                                                 unsigned short* __restrict__ w1mt) {
  int bid = blockIdx.x, tid = threadIdx.x;
  if (bid < 576) {
    __shared__ float tile[32][33];
    int bx = bid % 24, by = bid / 24;
    int tx = tid & 31, ty = tid >> 5;
    for (int j = 0; j < 32; j += 8)
      tile[ty + j][tx] = W1[(size_t)(by * 32 + ty + j) * ND + bx * 32 + tx];
    __syncthreads();
    for (int j = 0; j < 32; j += 8)
      w1mt[(size_t)(bx * 32 + ty + j) * ND + by * 32 + tx] = bf16b(tile[tx][ty + j]);
  } else {
    int b = bid - 576;
    __shared__ int red[256];
    __shared__ float sh_inva;
    int cnt = 0;
    for (int j = tid; j < NS; j += 256) cnt += (ids[b * NS + j] != 0);
    red[tid] = cnt;
    __syncthreads();
    for (int s = 128; s > 0; s >>= 1) {
      if (tid < s) red[tid] += red[tid + s];
      __syncthreads();
    }
    if (tid == 0) {
      int mlen = red[0];
      int acnt = 0;
      for (int t = 0; t < NTA; ++t) acnt += (tids[b * NTA + t] != 0);
      lens[b] = (float)mlen;
      lens[64 + b] = 1.0f / (float)mlen;
      float inva = 1.0f / (float)acnt;
      lens[128 + b] = inva;
      sh_inva = inva;
    }
    __syncthreads();
    float inva = sh_inva;
    for (int j = tid; j < ND; j += 256) {
      float s = 0.f;
      for (int t = 0; t < NTA; ++t) s += aspect[((size_t)b * NTA + t) * ND + j];
      v_a[b * ND + j] = s * inva;
    }
  }
}

// ---------- v_s (mean of memory) + m' = bf16(memory * loc) ----------
// Grid (16,64), 192 thr. Each thread owns 8 consecutive floats (d0 = (tid%96)*8)
// over 16 rows (half = tid/96) -> mp written as 16B uint4 per row.
__global__ __launch_bounds__(192) void k_vs_mprime(const float* __restrict__ memory,
                                                   const float* __restrict__ lens,
                                                   float* __restrict__ v_s,
                                                   unsigned short* __restrict__ mp) {
  int sc = blockIdx.x, b = blockIdx.y, tid = threadIdx.x;
  int dq = tid % 96, half = tid / 96;
  int d0 = dq * 8;
  float inv_mlen = lens[64 + b];
  float mlenf = lens[b];
  float s0 = 0, s1 = 0, s2 = 0, s3 = 0, s4 = 0, s5 = 0, s6 = 0, s7 = 0;
  int sbase = sc * 32 + half * 16;
#pragma unroll 4
  for (int s = 0; s < 16; ++s) {
    int srow = sbase + s;
    size_t row = (size_t)b * NS + srow;
    const float4 va = *(const float4*)(memory + row * ND + d0);
    const float4 vb = *(const float4*)(memory + row * ND + d0 + 4);
    s0 += va.x; s1 += va.y; s2 += va.z; s3 += va.w;
    s4 += vb.x; s5 += vb.y; s6 += vb.z; s7 += vb.w;
    float fs = (float)srow;
    float loc = (fs < mlenf) ? 1.0f - fs * inv_mlen : 1.0f;
    uint4 pk;
    pk.x = bfpack2(va.x * loc, va.y * loc);
    pk.y = bfpack2(va.z * loc, va.w * loc);
    pk.z = bfpack2(vb.x * loc, vb.y * loc);
    pk.w = bfpack2(vb.z * loc, vb.w * loc);
    *(uint4*)(mp + row * ND + d0) = pk;
  }
  float* p = v_s + b * ND + d0;
  atomicAdd(p + 0, s0 * inv_mlen);
  atomicAdd(p + 1, s1 * inv_mlen);
  atomicAdd(p + 2, s2 * inv_mlen);
  atomicAdd(p + 3, s3 * inv_mlen);
  atomicAdd(p + 4, s4 * inv_mlen);
  atomicAdd(p + 5, s5 * inv_mlen);
  atomicAdd(p + 6, s6 * inv_mlen);
  atomicAdd(p + 7, s7 * inv_mlen);
}

// ---------- ctx += partial( [v_a;v_s] @ [W1_a;W1_s] ), split-K over 4 chunks ----------
// b-FASTEST grid (64,6,4): the 64 blocks sharing one 384x128 W1 panel are
// dispatch-adjacent -> each XCD L2 pulls the panel once (8x), not 64x.
__global__ __launch_bounds__(128) void k_ctx(const float* __restrict__ W1,
                                             const float* __restrict__ v_a,
                                             const float* __restrict__ v_s,
                                             float* __restrict__ ctx) {
  int b = blockIdx.x, et = blockIdx.y, dc = blockIdx.z, tid = threadIdx.x;
  __shared__ float vbuf[384];
  for (int j = tid; j < 384; j += 128) {
    int k = dc * 384 + j;
    vbuf[j] = (k < ND) ? v_a[b * ND + k] : v_s[b * ND + (k - ND)];
  }
  __syncthreads();
  int e = et * 128 + tid;
  float acc = 0.f;
  const float* Wk = W1 + (size_t)(ND + dc * 384) * ND + e;  // rows 768.. of W1 = [W1_a; W1_s]
#pragma unroll 8
  for (int j = 0; j < 384; ++j) acc += vbuf[j] * Wk[(size_t)j * ND];
  atomicAdd(&ctx[b * ND + e], acc);
}

// ---------- big GEMM: scores[row] += sum_e tanh((m'@W1_m)[row,e]+ctx+b1)*w2[e] ----------
// 128x128 tile, BK=64, 4 waves (2x2), 16x16x32 bf16 MFMA, global_load_lds w=16.
// K-loop: the twice-measured 63.5us structure — prefetch issued BEFORE
// ds_read+MFMA, ONE __syncthreads per K-step (its implicit vmcnt(0)+lgkmcnt(0)
// drain is the proven-cheapest sync here; raw-barrier/counted-vmcnt variants
// measured 82us). XCD swizzle + et-fastest (FETCH 29.5MB, L2-resident operands).
__global__ __launch_bounds__(256) void k_gemm_scores(const unsigned short* __restrict__ mp,
                                                     const unsigned short* __restrict__ w1mt,
                                                     const float* __restrict__ ctx,
                                                     const float* __restrict__ b1,
                                                     const float* __restrict__ w2,
                                                     float* __restrict__ scores) {
  __shared__ char lds[65536];
  const int tid = threadIdx.x;
  const int wave = tid >> 6, lane = tid & 63;
  const int bid = blockIdx.x;
  const int swz = (bid & 7) * 192 + (bid >> 3);
  const int rt = swz / 6;          // M-tile (slow)
  const int et = swz - rt * 6;     // N-tile (fast: same-A blocks adjacent)
  const int row0 = rt * 128, n0 = et * 128;
  const int b = row0 >> 9;  // 128 | 512: tile never crosses a batch
  const int wm = wave & 1, wn = wave >> 1;

  // staging: each issue = 64 lanes x 16B = 8 rows x 8 chunks
  const int lrow = lane >> 3;                 // 0..7 row within issue
  const int qlog = (lane & 7) ^ lrow;         // logical chunk for this phys slot
  const char* Abase = (const char*)mp + (size_t)(row0 + lrow) * (ND * 2) + qlog * 16;
  const char* Bbase = (const char*)w1mt + (size_t)(n0 + lrow) * (ND * 2) + qlog * 16;

  f32x4 acc[4][4];
#pragma unroll
  for (int i = 0; i < 4; ++i)
#pragma unroll
    for (int t = 0; t < 4; ++t) acc[i][t] = (f32x4){0.f, 0.f, 0.f, 0.f};

  const int q2 = lane >> 4, c = lane & 15;
  int offA[4][2], offB[4][2];
#pragma unroll
  for (int i = 0; i < 4; ++i) {
    int ml = wm * 64 + i * 16 + c;
    offA[i][0] = ml * 128 + ((q2 ^ (ml & 7)) * 16);
    offA[i][1] = ml * 128 + (((4 + q2) ^ (ml & 7)) * 16);
    int nl = wn * 64 + i * 16 + c;
    offB[i][0] = nl * 128 + ((q2 ^ (nl & 7)) * 16);
    offB[i][1] = nl * 128 + (((4 + q2) ^ (nl & 7)) * 16);
  }

  auto stage = [&](int bufsel, int kb) {
    char* lA = lds + bufsel * 32768;
    char* lB = lA + 16384;
#pragma unroll
    for (int i = 0; i < 4; ++i) {
      int g = wave * 4 + i;
      async_copy16(Abase + (size_t)g * 8 * (ND * 2) + kb, lA + g * 1024);
      async_copy16(Bbase + (size_t)g * 8 * (ND * 2) + kb, lB + g * 1024);
    }
  };

  // prologue: fill buffer 0
  stage(0, 0);
  __syncthreads();

  int cur = 0;
#pragma unroll 2
  for (int t = 0; t < 12; ++t) {  // 12 K-steps of 64 k (128 B/row)
    if (t < 11) stage(cur ^ 1, (t + 1) * 128);  // prefetch next tile (in flight over MFMA)
    const char* lA = lds + cur * 32768;
    const char* lB = lA + 16384;
    bf16x8 af[2][4], bfr[2][4];
#pragma unroll
    for (int kk = 0; kk < 2; ++kk)
#pragma unroll
      for (int i = 0; i < 4; ++i) {
        af[kk][i] = *(const bf16x8*)(lA + offA[i][kk]);
        bfr[kk][i] = *(const bf16x8*)(lB + offB[i][kk]);
      }
#pragma unroll
    for (int kk = 0; kk < 2; ++kk)
#pragma unroll
      for (int i = 0; i < 4; ++i)
#pragma unroll
        for (int t2 = 0; t2 < 4; ++t2)
          acc[i][t2] = __builtin_amdgcn_mfma_f32_16x16x32_bf16(af[kk][i], bfr[kk][t2], acc[i][t2], 0, 0, 0);
    // one barrier per K-step: implicit vmcnt(0) drains the prefetch, and the
    // join guarantees all waves finished reading buf[cur] before it is restaged.
    __syncthreads();
    cur ^= 1;
  }

  // epilogue: C/D layout row = q2*4+r, col = c
  float ctxv[4], w2v[4];
#pragma unroll
  for (int t = 0; t < 4; ++t) {
    int n = n0 + wn * 64 + t * 16 + c;
    ctxv[t] = ctx[b * ND + n] + b1[n];
    w2v[t] = w2[n];
  }
#pragma unroll
  for (int i = 0; i < 4; ++i) {
#pragma unroll
    for (int r = 0; r < 4; ++r) {
      float s = 0.f;
#pragma unroll
      for (int t = 0; t < 4; ++t) s += fast_tanh(acc[i][t][r] + ctxv[t]) * w2v[t];
      s += __shfl_xor(s, 1, 64);
      s += __shfl_xor(s, 2, 64);
      s += __shfl_xor(s, 4, 64);
      s += __shfl_xor(s, 8, 64);
      if (c == 0) atomicAdd(&scores[row0 + wm * 64 + i * 16 + q2 * 4 + r], s);
    }
  }
}

// ---------- fused softmax + v_ts = sum_s alpha * m' ----------
// Block recomputes softmax stats from scores[b][:], then 16B uint4 mp loads:
// thread owns 8 consecutive bf16 (d0 = (tid%96)*8) over 16 rows (tid/96).
__global__ __launch_bounds__(192) void k_vts(const unsigned short* __restrict__ mp,
                                             const float* __restrict__ scores,
                                             float* __restrict__ v_ts) {
  int sc = blockIdx.x, b = blockIdx.y, tid = threadIdx.x;
  int lane = tid & 63, wid = tid >> 6;
  __shared__ float sred[3], sred2[3];
  __shared__ float al[32];
  float v0 = scores[b * NS + tid];
  float v1 = scores[b * NS + tid + 192];
  float v2 = (tid < 128) ? scores[b * NS + tid + 384] : -1e30f;
  float m = fmaxf(fmaxf(v0, v1), v2);
  for (int off = 1; off < 64; off <<= 1) m = fmaxf(m, __shfl_xor(m, off, 64));
  if (lane == 0) sred[wid] = m;
  __syncthreads();
  float M = fmaxf(fmaxf(sred[0], sred[1]), sred[2]);
  float e = __expf(v0 - M) + __expf(v1 - M) + ((tid < 128) ? __expf(v2 - M) : 0.f);
  for (int off = 1; off < 64; off <<= 1) e += __shfl_xor(e, off, 64);
  if (lane == 0) sred2[wid] = e;
  __syncthreads();
  float invS = 1.0f / (sred2[0] + sred2[1] + sred2[2]);
  if (tid < 32) al[tid] = __expf(scores[b * NS + sc * 32 + tid] - M) * invS;
  __syncthreads();

  int dq = tid % 96, half = tid / 96;
  int d0 = dq * 8;
  float a0 = 0, a1 = 0, a2 = 0, a3 = 0, a4 = 0, a5 = 0, a6 = 0, a7 = 0;
  int sbase = half * 16;
#pragma unroll 4
  for (int s = 0; s < 16; ++s) {
    size_t row = (size_t)b * NS + sc * 32 + sbase + s;
    uint4 pk = *(const uint4*)(mp + row * ND + d0);
    float a = al[sbase + s];
    a0 += a * __uint_as_float(pk.x << 16);
    a1 += a * __uint_as_float(pk.x & 0xFFFF0000u);
    a2 += a * __uint_as_float(pk.y << 16);
    a3 += a * __uint_as_float(pk.y & 0xFFFF0000u);
    a4 += a * __uint_as_float(pk.z << 16);
    a5 += a * __uint_as_float(pk.z & 0xFFFF0000u);
    a6 += a * __uint_as_float(pk.w << 16);
    a7 += a * __uint_as_float(pk.w & 0xFFFF0000u);
  }
  float* p = v_ts + b * ND + d0;
  atomicAdd(p + 0, a0);
  atomicAdd(p + 1, a1);
  atomicAdd(p + 2, a2);
  atomicAdd(p + 3, a3);
  atomicAdd(p + 4, a4);
  atomicAdd(p + 5, a5);
  atomicAdd(p + 6, a6);
  atomicAdd(p + 7, a7);
}

// ---------- u += partial( (v_ts+v_s) @ Wm ), split-K over 4 chunks ----------
// b-FASTEST grid (64,6,4): 64 blocks sharing a 192x128 Wm panel adjacent.
__global__ __launch_bounds__(128) void k_final1(const float* __restrict__ v_ts,
                                                const float* __restrict__ v_s,
                                                const float* __restrict__ Wm,
                                                float* __restrict__ u) {
  int b = blockIdx.x, et = blockIdx.y, dc = blockIdx.z, tid = threadIdx.x;
  __shared__ float vbuf[192];
  for (int j = tid; j < 192; j += 128) {
    int d = dc * 192 + j;
    vbuf[j] = v_ts[b * ND + d] + v_s[b * ND + d];
  }
  __syncthreads();
  int e = et * 128 + tid;
  float acc = 0.f;
  const float* Wk = Wm + (size_t)(dc * 192) * ND + e;
#pragma unroll 8
  for (int j = 0; j < 192; ++j) acc += vbuf[j] * Wk[(size_t)j * ND];
  atomicAdd(&u[b * ND + e], acc);
}

// ---------- logits = tanh(u+bm) @ Wd + bd ----------
__global__ __launch_bounds__(256) void k_final2(const float* __restrict__ u,
                                                const float* __restrict__ bm,
                                                const float* __restrict__ Wd,
                                                const float* __restrict__ bd,
                                                float* __restrict__ out) {
  int b = blockIdx.x, tid = threadIdx.x;
  int wid = tid >> 6, lane = tid & 63;
  __shared__ float red[4][3];
  float p0 = 0, p1 = 0, p2 = 0;
  for (int e = tid; e < ND; e += 256) {
    float vm = fast_tanh(u[b * ND + e] + bm[e]);
    p0 += vm * Wd[e * 3 + 0];
    p1 += vm * Wd[e * 3 + 1];
    p2 += vm * Wd[e * 3 + 2];
  }
  for (int off = 1; off < 64; off <<= 1) {
    p0 += __shfl_xor(p0, off, 64);
    p1 += __shfl_xor(p1, off, 64);
    p2 += __shfl_xor(p2, off, 64);
  }
  if (lane == 0) { red[wid][0] = p0; red[wid][1] = p1; red[wid][2] = p2; }
  __syncthreads();
  if (tid == 0) {
    out[b * 3 + 0] = red[0][0] + red[1][0] + red[2][0] + red[3][0] + bd[0];
    out[b * 3 + 1] = red[0][1] + red[1][1] + red[2][1] + red[3][1] + bd[1];
    out[b * 3 + 2] = red[0][2] + red[1][2] + red[2][2] + red[3][2] + bd[2];
  }
}

extern "C" void kernel_launch(void* const* d_in, const int* in_sizes, int n_in,
                              void* d_out, int out_size, void* d_ws, size_t ws_size,
                              hipStream_t stream) {
  const float* memory = (const float*)d_in[0];
  const float* aspect = (const float*)d_in[1];
  const int* ids = (const int*)d_in[2];
  const int* tids = (const int*)d_in[3];
  const float* W1 = (const float*)d_in[4];
  const float* b1 = (const float*)d_in[5];
  const float* w2 = (const float*)d_in[6];
  const float* Wm = (const float*)d_in[7];
  const float* bm = (const float*)d_in[8];
  const float* Wd = (const float*)d_in[9];
  const float* bd = (const float*)d_in[10];
  float* out = (float*)d_out;

  char* ws = (char*)d_ws;
  float* scores = (float*)(ws + OFF_SCORES);
  float* v_s = (float*)(ws + OFF_VS);
  float* v_ts = (float*)(ws + OFF_VTS);
  float* ctx = (float*)(ws + OFF_CTX);
  float* u = (float*)(ws + OFF_U);
  float* v_a = (float*)(ws + OFF_VA);
  float* lens = (float*)(ws + OFF_LENS);
  unsigned short* w1mt = (unsigned short*)(ws + OFF_W1MT);
  unsigned short* mp = (unsigned short*)(ws + OFF_MP);

  hipMemsetAsync(ws, 0, ZERO_BYTES, stream);

  k_prep_tr<<<640, 256, 0, stream>>>(ids, tids, aspect, W1, v_a, lens, w1mt);
  k_vs_mprime<<<dim3(16, NB), 192, 0, stream>>>(memory, lens, v_s, mp);
  k_ctx<<<dim3(64, 6, 4), 128, 0, stream>>>(W1, v_a, v_s, ctx);
  k_gemm_scores<<<1536, 256, 0, stream>>>(mp, w1mt, ctx, b1, w2, scores);
  k_vts<<<dim3(16, NB), 192, 0, stream>>>(mp, scores, v_ts);
  k_final1<<<dim3(64, 6, 4), 128, 0, stream>>>(v_ts, v_s, Wm, u);
  k_final2<<<NB, 256, 0, stream>>>(u, bm, Wd, bd, out);
}

// Round 8
// 305.476 us; speedup vs baseline: 1.2032x; 1.2032x over previous
//
#include <hip/hip_runtime.h>
#include <hip/hip_bf16.h>

// Cabasc: B=64, S=512, Ta=8, D=768
// Round 10: NO-ATOMICS sweep. R7 found atomics write-through to HBM
//   (WRITE_SIZE 96MB for 48MB of stores = cross-XCD atomic line flushes).
//   Every split-K accumulator (v_s, v_ts, ctx, u, scores) -> partials buffer
//   with plain stores; consumer folds the (L2-resident) reduction.
//   No buffer needs zeroing -> hipMemsetAsync dropped.
//   vs_mprime/vts reverted to uint2 / 32-row / unroll-8 (uint4 form regressed).
//   Gemm: twice-measured 63.5us __syncthreads 2-phase, untouched.

#define NB 64
#define NS 512
#define ND 768
#define NTA 8

typedef __attribute__((ext_vector_type(8))) __bf16 bf16x8;
typedef __attribute__((ext_vector_type(4))) float f32x4;

// ---- workspace layout (bytes), all buffers fully written before read ----
#define OFF_PVS 0u              // part_vs  [16][NB][ND] f32 = 3145728
#define OFF_PVTS 3145728u       // part_vts [16][NB][ND] f32 = 3145728
#define OFF_PCTX 6291456u       // ctx_part [4][NB][ND] f32  = 786432
#define OFF_PU 7077888u         // u_part   [4][NB][ND] f32  = 786432
#define OFF_PSC 7864320u        // sc_part  [12][NB][NS] f32 = 1572864
#define OFF_VS 9437184u         // v_s  NB*ND f32 = 196608
#define OFF_VA 9633792u         // v_a  NB*ND f32 = 196608
#define OFF_LENS 9830400u       // mlenf[64] | inv_mlen[64] | inv_alen[64]
#define OFF_W1MT 9831424u       // ND*ND bf16 = 1179648
#define OFF_MP 11011072u        // NB*NS*ND bf16 = 50331648 (total ~61.3 MB)

__device__ __forceinline__ float fast_tanh(float x) {
  x = fminf(fmaxf(x, -15.f), 15.f);
  float t = __expf(2.f * x);
  return __fdividef(t - 1.f, t + 1.f);
}

__device__ __forceinline__ unsigned bfpack2(float a, float b) {
  unsigned ua = __float_as_uint(a), ub = __float_as_uint(b);
  ua = (ua + 0x7FFFu + ((ua >> 16) & 1u)) >> 16;
  ub = (ub + 0x7FFFu + ((ub >> 16) & 1u)) >> 16;
  return ua | (ub << 16);
}

__device__ __forceinline__ unsigned short bf16b(float f) {
  unsigned u = __float_as_uint(f);
  u = (u + 0x7FFFu + ((u >> 16) & 1u)) >> 16;
  return (unsigned short)u;
}

__device__ __forceinline__ void async_copy16(const void* g, void* l) {
  __builtin_amdgcn_global_load_lds(
      (const __attribute__((address_space(1))) void*)g,
      (__attribute__((address_space(3))) void*)l, 16, 0, 0);
}

// ---------- fused: W1_m transpose (blocks 0..575) + lens/v_a prep (blocks 576..639) ----------
__global__ __launch_bounds__(256) void k_prep_tr(const int* __restrict__ ids,
                                                 const int* __restrict__ tids,
                                                 const float* __restrict__ aspect,
                                                 const float* __restrict__ W1,
                                                 float* __restrict__ v_a,
                                                 float* __restrict__ lens,
                                                 unsigned short* __restrict__ w1mt) {
  int bid = blockIdx.x, tid = threadIdx.x;
  if (bid < 576) {
    __shared__ float tile[32][33];
    int bx = bid % 24, by = bid / 24;
    int tx = tid & 31, ty = tid >> 5;
    for (int j = 0; j < 32; j += 8)
      tile[ty + j][tx] = W1[(size_t)(by * 32 + ty + j) * ND + bx * 32 + tx];
    __syncthreads();
    for (int j = 0; j < 32; j += 8)
      w1mt[(size_t)(bx * 32 + ty + j) * ND + by * 32 + tx] = bf16b(tile[tx][ty + j]);
  } else {
    int b = bid - 576;
    __shared__ int red[256];
    __shared__ float sh_inva;
    int cnt = 0;
    for (int j = tid; j < NS; j += 256) cnt += (ids[b * NS + j] != 0);
    red[tid] = cnt;
    __syncthreads();
    for (int s = 128; s > 0; s >>= 1) {
      if (tid < s) red[tid] += red[tid + s];
      __syncthreads();
    }
    if (tid == 0) {
      int mlen = red[0];
      int acnt = 0;
      for (int t = 0; t < NTA; ++t) acnt += (tids[b * NTA + t] != 0);
      lens[b] = (float)mlen;
      lens[64 + b] = 1.0f / (float)mlen;
      float inva = 1.0f / (float)acnt;
      lens[128 + b] = inva;
      sh_inva = inva;
    }
    __syncthreads();
    float inva = sh_inva;
    for (int j = tid; j < ND; j += 256) {
      float s = 0.f;
      for (int t = 0; t < NTA; ++t) s += aspect[((size_t)b * NTA + t) * ND + j];
      v_a[b * ND + j] = s * inva;
    }
  }
}

// ---------- v_s partials + m' = bf16(memory * loc) ----------
// uint2 / 32-row / unroll-8 (proven form); NO atomics: one float4 partial store.
__global__ __launch_bounds__(192) void k_vs_mprime(const float* __restrict__ memory,
                                                   const float* __restrict__ lens,
                                                   float* __restrict__ part_vs,
                                                   unsigned short* __restrict__ mp) {
  int sc = blockIdx.x, b = blockIdx.y, tid = threadIdx.x;
  int d0 = tid * 4;
  float inv_mlen = lens[64 + b];
  float mlenf = lens[b];
  float s0 = 0, s1 = 0, s2 = 0, s3 = 0;
#pragma unroll 8
  for (int s = 0; s < 32; ++s) {
    int srow = sc * 32 + s;
    size_t row = (size_t)b * NS + srow;
    const float4 v = *(const float4*)(memory + row * ND + d0);
    s0 += v.x; s1 += v.y; s2 += v.z; s3 += v.w;
    float fs = (float)srow;
    float loc = (fs < mlenf) ? 1.0f - fs * inv_mlen : 1.0f;
    uint2 pk;
    pk.x = bfpack2(v.x * loc, v.y * loc);
    pk.y = bfpack2(v.z * loc, v.w * loc);
    *(uint2*)(mp + row * ND + d0) = pk;
  }
  float4 o;
  o.x = s0 * inv_mlen; o.y = s1 * inv_mlen; o.z = s2 * inv_mlen; o.w = s3 * inv_mlen;
  *(float4*)(part_vs + ((size_t)sc * NB + b) * ND + d0) = o;
}

// ---------- v_s = sum of 16 partials ----------
__global__ __launch_bounds__(192) void k_reduce_vs(const float* __restrict__ part_vs,
                                                   float* __restrict__ v_s) {
  int b = blockIdx.x, tid = threadIdx.x;
  int d0 = tid * 4;
  float a0 = 0, a1 = 0, a2 = 0, a3 = 0;
#pragma unroll
  for (int p = 0; p < 16; ++p) {
    const float4 v = *(const float4*)(part_vs + ((size_t)p * NB + b) * ND + d0);
    a0 += v.x; a1 += v.y; a2 += v.z; a3 += v.w;
  }
  float4 o; o.x = a0; o.y = a1; o.z = a2; o.w = a3;
  *(float4*)(v_s + b * ND + d0) = o;
}

// ---------- ctx_part[dc] = partial( [v_a;v_s] @ [W1_a;W1_s] ) ----------
// b-FASTEST grid (64,6,4); plain store (no atomics).
__global__ __launch_bounds__(128) void k_ctx(const float* __restrict__ W1,
                                             const float* __restrict__ v_a,
                                             const float* __restrict__ v_s,
                                             float* __restrict__ ctx_part) {
  int b = blockIdx.x, et = blockIdx.y, dc = blockIdx.z, tid = threadIdx.x;
  __shared__ float vbuf[384];
  for (int j = tid; j < 384; j += 128) {
    int k = dc * 384 + j;
    vbuf[j] = (k < ND) ? v_a[b * ND + k] : v_s[b * ND + (k - ND)];
  }
  __syncthreads();
  int e = et * 128 + tid;
  float acc = 0.f;
  const float* Wk = W1 + (size_t)(ND + dc * 384) * ND + e;  // rows 768.. of W1 = [W1_a; W1_s]
#pragma unroll 8
  for (int j = 0; j < 384; ++j) acc += vbuf[j] * Wk[(size_t)j * ND];
  ctx_part[((size_t)dc * NB + b) * ND + e] = acc;
}

// ---------- big GEMM: sc_part[et*2+wn][row] = sum_e tanh((m'@W1_m)+ctx+b1)*w2 ----------
// 128x128 tile, BK=64, 4 waves (2x2), 16x16x32 bf16 MFMA, global_load_lds w=16.
// Twice-measured 63.5us __syncthreads 2-phase. XCD swizzle + et-fastest.
// Epilogue: ctx = sum of 4 partials (L2-hit); scores stored per (et,wn) partial.
__global__ __launch_bounds__(256) void k_gemm_scores(const unsigned short* __restrict__ mp,
                                                     const unsigned short* __restrict__ w1mt,
                                                     const float* __restrict__ ctx_part,
                                                     const float* __restrict__ b1,
                                                     const float* __restrict__ w2,
                                                     float* __restrict__ sc_part) {
  __shared__ char lds[65536];
  const int tid = threadIdx.x;
  const int wave = tid >> 6, lane = tid & 63;
  const int bid = blockIdx.x;
  const int swz = (bid & 7) * 192 + (bid >> 3);
  const int rt = swz / 6;          // M-tile (slow)
  const int et = swz - rt * 6;     // N-tile (fast: same-A blocks adjacent)
  const int row0 = rt * 128, n0 = et * 128;
  const int b = row0 >> 9;  // 128 | 512: tile never crosses a batch
  const int wm = wave & 1, wn = wave >> 1;

  // staging: each issue = 64 lanes x 16B = 8 rows x 8 chunks
  const int lrow = lane >> 3;                 // 0..7 row within issue
  const int qlog = (lane & 7) ^ lrow;         // logical chunk for this phys slot
  const char* Abase = (const char*)mp + (size_t)(row0 + lrow) * (ND * 2) + qlog * 16;
  const char* Bbase = (const char*)w1mt + (size_t)(n0 + lrow) * (ND * 2) + qlog * 16;

  f32x4 acc[4][4];
#pragma unroll
  for (int i = 0; i < 4; ++i)
#pragma unroll
    for (int t = 0; t < 4; ++t) acc[i][t] = (f32x4){0.f, 0.f, 0.f, 0.f};

  const int q2 = lane >> 4, c = lane & 15;
  int offA[4][2], offB[4][2];
#pragma unroll
  for (int i = 0; i < 4; ++i) {
    int ml = wm * 64 + i * 16 + c;
    offA[i][0] = ml * 128 + ((q2 ^ (ml & 7)) * 16);
    offA[i][1] = ml * 128 + (((4 + q2) ^ (ml & 7)) * 16);
    int nl = wn * 64 + i * 16 + c;
    offB[i][0] = nl * 128 + ((q2 ^ (nl & 7)) * 16);
    offB[i][1] = nl * 128 + (((4 + q2) ^ (nl & 7)) * 16);
  }

  auto stage = [&](int bufsel, int kb) {
    char* lA = lds + bufsel * 32768;
    char* lB = lA + 16384;
#pragma unroll
    for (int i = 0; i < 4; ++i) {
      int g = wave * 4 + i;
      async_copy16(Abase + (size_t)g * 8 * (ND * 2) + kb, lA + g * 1024);
      async_copy16(Bbase + (size_t)g * 8 * (ND * 2) + kb, lB + g * 1024);
    }
  };

  // prologue: fill buffer 0
  stage(0, 0);
  __syncthreads();

  int cur = 0;
#pragma unroll 2
  for (int t = 0; t < 12; ++t) {  // 12 K-steps of 64 k (128 B/row)
    if (t < 11) stage(cur ^ 1, (t + 1) * 128);  // prefetch next tile (in flight over MFMA)
    const char* lA = lds + cur * 32768;
    const char* lB = lA + 16384;
    bf16x8 af[2][4], bfr[2][4];
#pragma unroll
    for (int kk = 0; kk < 2; ++kk)
#pragma unroll
      for (int i = 0; i < 4; ++i) {
        af[kk][i] = *(const bf16x8*)(lA + offA[i][kk]);
        bfr[kk][i] = *(const bf16x8*)(lB + offB[i][kk]);
      }
#pragma unroll
    for (int kk = 0; kk < 2; ++kk)
#pragma unroll
      for (int i = 0; i < 4; ++i)
#pragma unroll
        for (int t2 = 0; t2 < 4; ++t2)
          acc[i][t2] = __builtin_amdgcn_mfma_f32_16x16x32_bf16(af[kk][i], bfr[kk][t2], acc[i][t2], 0, 0, 0);
    __syncthreads();
    cur ^= 1;
  }

  // epilogue: C/D layout row = q2*4+r, col = c
  float ctxv[4], w2v[4];
#pragma unroll
  for (int t = 0; t < 4; ++t) {
    int n = n0 + wn * 64 + t * 16 + c;
    float cx = b1[n];
#pragma unroll
    for (int dc = 0; dc < 4; ++dc) cx += ctx_part[((size_t)dc * NB + b) * ND + n];
    ctxv[t] = cx;
    w2v[t] = w2[n];
  }
  float* scp = sc_part + (size_t)(et * 2 + wn) * (NB * NS);
#pragma unroll
  for (int i = 0; i < 4; ++i) {
#pragma unroll
    for (int r = 0; r < 4; ++r) {
      float s = 0.f;
#pragma unroll
      for (int t = 0; t < 4; ++t) s += fast_tanh(acc[i][t][r] + ctxv[t]) * w2v[t];
      s += __shfl_xor(s, 1, 64);
      s += __shfl_xor(s, 2, 64);
      s += __shfl_xor(s, 4, 64);
      s += __shfl_xor(s, 8, 64);
      if (c == 0) scp[row0 + wm * 64 + i * 16 + q2 * 4 + r] = s;
    }
  }
}

// ---------- fused softmax + v_ts partials ----------
// scores(s) = sum of 12 partials (1.5MB, L2-resident). uint2 / 32-row form.
__global__ __launch_bounds__(192) void k_vts(const unsigned short* __restrict__ mp,
                                             const float* __restrict__ sc_part,
                                             float* __restrict__ part_vts) {
  int sc = blockIdx.x, b = blockIdx.y, tid = threadIdx.x;
  int lane = tid & 63, wid = tid >> 6;
  __shared__ float sred[3], sred2[3];
  __shared__ float al[32];
  const float* sp = sc_part + b * NS;
  float v0 = 0, v1 = 0, v2 = 0;
#pragma unroll
  for (int p = 0; p < 12; ++p) {
    const float* spp = sp + (size_t)p * (NB * NS);
    v0 += spp[tid];
    v1 += spp[tid + 192];
    if (tid < 128) v2 += spp[tid + 384];
  }
  if (tid >= 128) v2 = -1e30f;
  float m = fmaxf(fmaxf(v0, v1), v2);
  for (int off = 1; off < 64; off <<= 1) m = fmaxf(m, __shfl_xor(m, off, 64));
  if (lane == 0) sred[wid] = m;
  __syncthreads();
  float M = fmaxf(fmaxf(sred[0], sred[1]), sred[2]);
  float e = __expf(v0 - M) + __expf(v1 - M) + ((tid < 128) ? __expf(v2 - M) : 0.f);
  for (int off = 1; off < 64; off <<= 1) e += __shfl_xor(e, off, 64);
  if (lane == 0) sred2[wid] = e;
  __syncthreads();
  float invS = 1.0f / (sred2[0] + sred2[1] + sred2[2]);
  if (tid < 32) {
    float sv = 0;
#pragma unroll
    for (int p = 0; p < 12; ++p) sv += sp[(size_t)p * (NB * NS) + sc * 32 + tid];
    al[tid] = __expf(sv - M) * invS;
  }
  __syncthreads();

  int d0 = tid * 4;
  float a0 = 0, a1 = 0, a2 = 0, a3 = 0;
#pragma unroll 8
  for (int s = 0; s < 32; ++s) {
    size_t row = (size_t)b * NS + sc * 32 + s;
    uint2 pk = *(const uint2*)(mp + row * ND + d0);
    float a = al[s];
    a0 += a * __uint_as_float(pk.x << 16);
    a1 += a * __uint_as_float(pk.x & 0xFFFF0000u);
    a2 += a * __uint_as_float(pk.y << 16);
    a3 += a * __uint_as_float(pk.y & 0xFFFF0000u);
  }
  float4 o; o.x = a0; o.y = a1; o.z = a2; o.w = a3;
  *(float4*)(part_vts + ((size_t)sc * NB + b) * ND + d0) = o;
}

// ---------- u_part[dc] = partial( (v_ts+v_s) @ Wm ) ----------
// b-FASTEST (64,6,4); v_ts folded from 16 partials (L2-resident); plain store.
__global__ __launch_bounds__(128) void k_final1(const float* __restrict__ part_vts,
                                                const float* __restrict__ v_s,
                                                const float* __restrict__ Wm,
                                                float* __restrict__ u_part) {
  int b = blockIdx.x, et = blockIdx.y, dc = blockIdx.z, tid = threadIdx.x;
  __shared__ float vbuf[192];
  for (int j = tid; j < 192; j += 128) {
    int d = dc * 192 + j;
    float v = v_s[b * ND + d];
#pragma unroll
    for (int p = 0; p < 16; ++p) v += part_vts[((size_t)p * NB + b) * ND + d];
    vbuf[j] = v;
  }
  __syncthreads();
  int e = et * 128 + tid;
  float acc = 0.f;
  const float* Wk = Wm + (size_t)(dc * 192) * ND + e;
#pragma unroll 8
  for (int j = 0; j < 192; ++j) acc += vbuf[j] * Wk[(size_t)j * ND];
  u_part[((size_t)dc * NB + b) * ND + e] = acc;
}

// ---------- logits = tanh(sum u_part + bm) @ Wd + bd ----------
__global__ __launch_bounds__(256) void k_final2(const float* __restrict__ u_part,
                                                const float* __restrict__ bm,
                                                const float* __restrict__ Wd,
                                                const float* __restrict__ bd,
                                                float* __restrict__ out) {
  int b = blockIdx.x, tid = threadIdx.x;
  int wid = tid >> 6, lane = tid & 63;
  __shared__ float red[4][3];
  float p0 = 0, p1 = 0, p2 = 0;
  for (int e = tid; e < ND; e += 256) {
    float uv = bm[e];
#pragma unroll
    for (int dc = 0; dc < 4; ++dc) uv += u_part[((size_t)dc * NB + b) * ND + e];
    float vm = fast_tanh(uv);
    p0 += vm * Wd[e * 3 + 0];
    p1 += vm * Wd[e * 3 + 1];
    p2 += vm * Wd[e * 3 + 2];
  }
  for (int off = 1; off < 64; off <<= 1) {
    p0 += __shfl_xor(p0, off, 64);
    p1 += __shfl_xor(p1, off, 64);
    p2 += __shfl_xor(p2, off, 64);
  }
  if (lane == 0) { red[wid][0] = p0; red[wid][1] = p1; red[wid][2] = p2; }
  __syncthreads();
  if (tid == 0) {
    out[b * 3 + 0] = red[0][0] + red[1][0] + red[2][0] + red[3][0] + bd[0];
    out[b * 3 + 1] = red[0][1] + red[1][1] + red[2][1] + red[3][1] + bd[1];
    out[b * 3 + 2] = red[0][2] + red[1][2] + red[2][2] + red[3][2] + bd[2];
  }
}

extern "C" void kernel_launch(void* const* d_in, const int* in_sizes, int n_in,
                              void* d_out, int out_size, void* d_ws, size_t ws_size,
                              hipStream_t stream) {
  const float* memory = (const float*)d_in[0];
  const float* aspect = (const float*)d_in[1];
  const int* ids = (const int*)d_in[2];
  const int* tids = (const int*)d_in[3];
  const float* W1 = (const float*)d_in[4];
  const float* b1 = (const float*)d_in[5];
  const float* w2 = (const float*)d_in[6];
  const float* Wm = (const float*)d_in[7];
  const float* bm = (const float*)d_in[8];
  const float* Wd = (const float*)d_in[9];
  const float* bd = (const float*)d_in[10];
  float* out = (float*)d_out;

  char* ws = (char*)d_ws;
  float* part_vs = (float*)(ws + OFF_PVS);
  float* part_vts = (float*)(ws + OFF_PVTS);
  float* ctx_part = (float*)(ws + OFF_PCTX);
  float* u_part = (float*)(ws + OFF_PU);
  float* sc_part = (float*)(ws + OFF_PSC);
  float* v_s = (float*)(ws + OFF_VS);
  float* v_a = (float*)(ws + OFF_VA);
  float* lens = (float*)(ws + OFF_LENS);
  unsigned short* w1mt = (unsigned short*)(ws + OFF_W1MT);
  unsigned short* mp = (unsigned short*)(ws + OFF_MP);

  // no memset: every workspace buffer is fully written before it is read.

  k_prep_tr<<<640, 256, 0, stream>>>(ids, tids, aspect, W1, v_a, lens, w1mt);
  k_vs_mprime<<<dim3(16, NB), 192, 0, stream>>>(memory, lens, part_vs, mp);
  k_reduce_vs<<<NB, 192, 0, stream>>>(part_vs, v_s);
  k_ctx<<<dim3(64, 6, 4), 128, 0, stream>>>(W1, v_a, v_s, ctx_part);
  k_gemm_scores<<<1536, 256, 0, stream>>>(mp, w1mt, ctx_part, b1, w2, sc_part);
  k_vts<<<dim3(16, NB), 192, 0, stream>>>(mp, sc_part, part_vts);
  k_final1<<<dim3(64, 6, 4), 128, 0, stream>>>(part_vts, v_s, Wm, u_part);
  k_final2<<<NB, 256, 0, stream>>>(u_part, bm, Wd, bd, out);
}

// Round 9
// 302.998 us; speedup vs baseline: 1.2130x; 1.0082x over previous
//
#include <hip/hip_runtime.h>
#include <hip/hip_bf16.h>

// Cabasc: B=64, S=512, Ta=8, D=768
// Round 11: gemm epilogue restored to R2-exact shape (single reduced ctx read;
//   new tiny k_reduce_ctx folds 4 partials + b1). Softmax fold de-duplicated
//   (k_softmax folds sc_part once -> alpha; k_vts is a pure stream).
//   vs_mprime: 2048 blocks / 16 rows / fully-unrolled uint2 / partial stores.
//   No atomics anywhere; no memset.

#define NB 64
#define NS 512
#define ND 768
#define NTA 8

typedef __attribute__((ext_vector_type(8))) __bf16 bf16x8;
typedef __attribute__((ext_vector_type(4))) float f32x4;

// ---- workspace layout (bytes), all buffers fully written before read ----
#define OFF_PVS 0u              // part_vs  [32][NB][ND] f32 = 6291456
#define OFF_PVTS 6291456u       // part_vts [16][NB][ND] f32 = 3145728
#define OFF_PCTX 9437184u       // ctx_part [4][NB][ND] f32  = 786432
#define OFF_CTX 10223616u       // ctx      [NB][ND] f32     = 196608 (b1 folded)
#define OFF_PU 10420224u        // u_part   [4][NB][ND] f32  = 786432
#define OFF_PSC 11206656u       // sc_part  [12][NB][NS] f32 = 1572864
#define OFF_ALPHA 12779520u     // alpha    [NB][NS] f32     = 131072
#define OFF_VS 12910592u        // v_s  NB*ND f32 = 196608
#define OFF_VA 13107200u        // v_a  NB*ND f32 = 196608
#define OFF_LENS 13303808u      // mlenf[64] | inv_mlen[64] | inv_alen[64]
#define OFF_W1MT 13304832u      // ND*ND bf16 = 1179648
#define OFF_MP 14484480u        // NB*NS*ND bf16 = 50331648 (total ~64.8 MB)

__device__ __forceinline__ float fast_tanh(float x) {
  x = fminf(fmaxf(x, -15.f), 15.f);
  float t = __expf(2.f * x);
  return __fdividef(t - 1.f, t + 1.f);
}

__device__ __forceinline__ unsigned bfpack2(float a, float b) {
  unsigned ua = __float_as_uint(a), ub = __float_as_uint(b);
  ua = (ua + 0x7FFFu + ((ua >> 16) & 1u)) >> 16;
  ub = (ub + 0x7FFFu + ((ub >> 16) & 1u)) >> 16;
  return ua | (ub << 16);
}

__device__ __forceinline__ unsigned short bf16b(float f) {
  unsigned u = __float_as_uint(f);
  u = (u + 0x7FFFu + ((u >> 16) & 1u)) >> 16;
  return (unsigned short)u;
}

__device__ __forceinline__ void async_copy16(const void* g, void* l) {
  __builtin_amdgcn_global_load_lds(
      (const __attribute__((address_space(1))) void*)g,
      (__attribute__((address_space(3))) void*)l, 16, 0, 0);
}

// ---------- fused: W1_m transpose (blocks 0..575) + lens/v_a prep (blocks 576..639) ----------
__global__ __launch_bounds__(256) void k_prep_tr(const int* __restrict__ ids,
                                                 const int* __restrict__ tids,
                                                 const float* __restrict__ aspect,
                                                 const float* __restrict__ W1,
                                                 float* __restrict__ v_a,
                                                 float* __restrict__ lens,
                                                 unsigned short* __restrict__ w1mt) {
  int bid = blockIdx.x, tid = threadIdx.x;
  if (bid < 576) {
    __shared__ float tile[32][33];
    int bx = bid % 24, by = bid / 24;
    int tx = tid & 31, ty = tid >> 5;
    for (int j = 0; j < 32; j += 8)
      tile[ty + j][tx] = W1[(size_t)(by * 32 + ty + j) * ND + bx * 32 + tx];
    __syncthreads();
    for (int j = 0; j < 32; j += 8)
      w1mt[(size_t)(bx * 32 + ty + j) * ND + by * 32 + tx] = bf16b(tile[tx][ty + j]);
  } else {
    int b = bid - 576;
    __shared__ int red[256];
    __shared__ float sh_inva;
    int cnt = 0;
    for (int j = tid; j < NS; j += 256) cnt += (ids[b * NS + j] != 0);
    red[tid] = cnt;
    __syncthreads();
    for (int s = 128; s > 0; s >>= 1) {
      if (tid < s) red[tid] += red[tid + s];
      __syncthreads();
    }
    if (tid == 0) {
      int mlen = red[0];
      int acnt = 0;
      for (int t = 0; t < NTA; ++t) acnt += (tids[b * NTA + t] != 0);
      lens[b] = (float)mlen;
      lens[64 + b] = 1.0f / (float)mlen;
      float inva = 1.0f / (float)acnt;
      lens[128 + b] = inva;
      sh_inva = inva;
    }
    __syncthreads();
    float inva = sh_inva;
    for (int j = tid; j < ND; j += 256) {
      float s = 0.f;
      for (int t = 0; t < NTA; ++t) s += aspect[((size_t)b * NTA + t) * ND + j];
      v_a[b * ND + j] = s * inva;
    }
  }
}

// ---------- v_s partials + m' = bf16(memory * loc) ----------
// Grid (32,64) = 2048 blocks, 16 rows each (6 waves/SIMD), fully unrolled.
__global__ __launch_bounds__(192) void k_vs_mprime(const float* __restrict__ memory,
                                                   const float* __restrict__ lens,
                                                   float* __restrict__ part_vs,
                                                   unsigned short* __restrict__ mp) {
  int sc = blockIdx.x, b = blockIdx.y, tid = threadIdx.x;
  int d0 = tid * 4;
  float inv_mlen = lens[64 + b];
  float mlenf = lens[b];
  float s0 = 0, s1 = 0, s2 = 0, s3 = 0;
#pragma unroll
  for (int s = 0; s < 16; ++s) {
    int srow = sc * 16 + s;
    size_t row = (size_t)b * NS + srow;
    const float4 v = *(const float4*)(memory + row * ND + d0);
    s0 += v.x; s1 += v.y; s2 += v.z; s3 += v.w;
    float fs = (float)srow;
    float loc = (fs < mlenf) ? 1.0f - fs * inv_mlen : 1.0f;
    uint2 pk;
    pk.x = bfpack2(v.x * loc, v.y * loc);
    pk.y = bfpack2(v.z * loc, v.w * loc);
    *(uint2*)(mp + row * ND + d0) = pk;
  }
  float4 o;
  o.x = s0 * inv_mlen; o.y = s1 * inv_mlen; o.z = s2 * inv_mlen; o.w = s3 * inv_mlen;
  *(float4*)(part_vs + ((size_t)sc * NB + b) * ND + d0) = o;
}

// ---------- v_s = sum of 32 partials ----------
__global__ __launch_bounds__(192) void k_reduce_vs(const float* __restrict__ part_vs,
                                                   float* __restrict__ v_s) {
  int b = blockIdx.x, tid = threadIdx.x;
  int d0 = tid * 4;
  float a0 = 0, a1 = 0, a2 = 0, a3 = 0;
#pragma unroll
  for (int p = 0; p < 32; ++p) {
    const float4 v = *(const float4*)(part_vs + ((size_t)p * NB + b) * ND + d0);
    a0 += v.x; a1 += v.y; a2 += v.z; a3 += v.w;
  }
  float4 o; o.x = a0; o.y = a1; o.z = a2; o.w = a3;
  *(float4*)(v_s + b * ND + d0) = o;
}

// ---------- ctx_part[dc] = partial( [v_a;v_s] @ [W1_a;W1_s] ) ----------
// b-FASTEST grid (64,6,4); plain store.
__global__ __launch_bounds__(128) void k_ctx(const float* __restrict__ W1,
                                             const float* __restrict__ v_a,
                                             const float* __restrict__ v_s,
                                             float* __restrict__ ctx_part) {
  int b = blockIdx.x, et = blockIdx.y, dc = blockIdx.z, tid = threadIdx.x;
  __shared__ float vbuf[384];
  for (int j = tid; j < 384; j += 128) {
    int k = dc * 384 + j;
    vbuf[j] = (k < ND) ? v_a[b * ND + k] : v_s[b * ND + (k - ND)];
  }
  __syncthreads();
  int e = et * 128 + tid;
  float acc = 0.f;
  const float* Wk = W1 + (size_t)(ND + dc * 384) * ND + e;  // rows 768.. of W1 = [W1_a; W1_s]
#pragma unroll 8
  for (int j = 0; j < 384; ++j) acc += vbuf[j] * Wk[(size_t)j * ND];
  ctx_part[((size_t)dc * NB + b) * ND + e] = acc;
}

// ---------- ctx = sum of 4 partials + b1 (pre-folded for the gemm epilogue) ----------
__global__ __launch_bounds__(192) void k_reduce_ctx(const float* __restrict__ ctx_part,
                                                    const float* __restrict__ b1,
                                                    float* __restrict__ ctx) {
  int b = blockIdx.x, tid = threadIdx.x;
  int d0 = tid * 4;
  const float4 bb = *(const float4*)(b1 + d0);
  float a0 = bb.x, a1 = bb.y, a2 = bb.z, a3 = bb.w;
#pragma unroll
  for (int p = 0; p < 4; ++p) {
    const float4 v = *(const float4*)(ctx_part + ((size_t)p * NB + b) * ND + d0);
    a0 += v.x; a1 += v.y; a2 += v.z; a3 += v.w;
  }
  float4 o; o.x = a0; o.y = a1; o.z = a2; o.w = a3;
  *(float4*)(ctx + b * ND + d0) = o;
}

// ---------- big GEMM: sc_part[et*2+wn][row] = sum_e tanh((m'@W1_m)+ctx)*w2 ----------
// 128x128 tile, BK=64, 4 waves (2x2), 16x16x32 bf16 MFMA, global_load_lds w=16.
// K-loop + epilogue shape = the twice-measured 63.5us R2 build (single ctx read,
// b1 pre-folded); scores stored as plain per-(et,wn) partials (no atomics).
__global__ __launch_bounds__(256) void k_gemm_scores(const unsigned short* __restrict__ mp,
                                                     const unsigned short* __restrict__ w1mt,
                                                     const float* __restrict__ ctx,
                                                     const float* __restrict__ w2,
                                                     float* __restrict__ sc_part) {
  __shared__ char lds[65536];
  const int tid = threadIdx.x;
  const int wave = tid >> 6, lane = tid & 63;
  const int bid = blockIdx.x;
  const int swz = (bid & 7) * 192 + (bid >> 3);
  const int rt = swz / 6;          // M-tile (slow)
  const int et = swz - rt * 6;     // N-tile (fast: same-A blocks adjacent)
  const int row0 = rt * 128, n0 = et * 128;
  const int b = row0 >> 9;  // 128 | 512: tile never crosses a batch
  const int wm = wave & 1, wn = wave >> 1;

  // staging: each issue = 64 lanes x 16B = 8 rows x 8 chunks
  const int lrow = lane >> 3;                 // 0..7 row within issue
  const int qlog = (lane & 7) ^ lrow;         // logical chunk for this phys slot
  const char* Abase = (const char*)mp + (size_t)(row0 + lrow) * (ND * 2) + qlog * 16;
  const char* Bbase = (const char*)w1mt + (size_t)(n0 + lrow) * (ND * 2) + qlog * 16;

  f32x4 acc[4][4];
#pragma unroll
  for (int i = 0; i < 4; ++i)
#pragma unroll
    for (int t = 0; t < 4; ++t) acc[i][t] = (f32x4){0.f, 0.f, 0.f, 0.f};

  const int q2 = lane >> 4, c = lane & 15;
  int offA[4][2], offB[4][2];
#pragma unroll
  for (int i = 0; i < 4; ++i) {
    int ml = wm * 64 + i * 16 + c;
    offA[i][0] = ml * 128 + ((q2 ^ (ml & 7)) * 16);
    offA[i][1] = ml * 128 + (((4 + q2) ^ (ml & 7)) * 16);
    int nl = wn * 64 + i * 16 + c;
    offB[i][0] = nl * 128 + ((q2 ^ (nl & 7)) * 16);
    offB[i][1] = nl * 128 + (((4 + q2) ^ (nl & 7)) * 16);
  }

  auto stage = [&](int bufsel, int kb) {
    char* lA = lds + bufsel * 32768;
    char* lB = lA + 16384;
#pragma unroll
    for (int i = 0; i < 4; ++i) {
      int g = wave * 4 + i;
      async_copy16(Abase + (size_t)g * 8 * (ND * 2) + kb, lA + g * 1024);
      async_copy16(Bbase + (size_t)g * 8 * (ND * 2) + kb, lB + g * 1024);
    }
  };

  // prologue: fill buffer 0
  stage(0, 0);
  __syncthreads();

  int cur = 0;
#pragma unroll 2
  for (int t = 0; t < 12; ++t) {  // 12 K-steps of 64 k (128 B/row)
    if (t < 11) stage(cur ^ 1, (t + 1) * 128);  // prefetch next tile (in flight over MFMA)
    const char* lA = lds + cur * 32768;
    const char* lB = lA + 16384;
    bf16x8 af[2][4], bfr[2][4];
#pragma unroll
    for (int kk = 0; kk < 2; ++kk)
#pragma unroll
      for (int i = 0; i < 4; ++i) {
        af[kk][i] = *(const bf16x8*)(lA + offA[i][kk]);
        bfr[kk][i] = *(const bf16x8*)(lB + offB[i][kk]);
      }
#pragma unroll
    for (int kk = 0; kk < 2; ++kk)
#pragma unroll
      for (int i = 0; i < 4; ++i)
#pragma unroll
        for (int t2 = 0; t2 < 4; ++t2)
          acc[i][t2] = __builtin_amdgcn_mfma_f32_16x16x32_bf16(af[kk][i], bfr[kk][t2], acc[i][t2], 0, 0, 0);
    __syncthreads();
    cur ^= 1;
  }

  // epilogue: C/D layout row = q2*4+r, col = c
  float ctxv[4], w2v[4];
#pragma unroll
  for (int t = 0; t < 4; ++t) {
    int n = n0 + wn * 64 + t * 16 + c;
    ctxv[t] = ctx[b * ND + n];
    w2v[t] = w2[n];
  }
  float* scp = sc_part + (size_t)(et * 2 + wn) * (NB * NS);
#pragma unroll
  for (int i = 0; i < 4; ++i) {
#pragma unroll
    for (int r = 0; r < 4; ++r) {
      float s = 0.f;
#pragma unroll
      for (int t = 0; t < 4; ++t) s += fast_tanh(acc[i][t][r] + ctxv[t]) * w2v[t];
      s += __shfl_xor(s, 1, 64);
      s += __shfl_xor(s, 2, 64);
      s += __shfl_xor(s, 4, 64);
      s += __shfl_xor(s, 8, 64);
      if (c == 0) scp[row0 + wm * 64 + i * 16 + q2 * 4 + r] = s;
    }
  }
}

// ---------- softmax: fold 12 score partials ONCE -> alpha ----------
__global__ __launch_bounds__(512) void k_softmax(const float* __restrict__ sc_part,
                                                 float* __restrict__ alpha) {
  int b = blockIdx.x, tid = threadIdx.x;
  int wid = tid >> 6, lane = tid & 63;
  __shared__ float red[8], red2[8];
  float v = 0.f;
#pragma unroll
  for (int p = 0; p < 12; ++p) v += sc_part[(size_t)p * (NB * NS) + b * NS + tid];
  float m = v;
  for (int off = 1; off < 64; off <<= 1) m = fmaxf(m, __shfl_xor(m, off, 64));
  if (lane == 0) red[wid] = m;
  __syncthreads();
  if (tid == 0) {
    float mm = red[0];
    for (int i = 1; i < 8; ++i) mm = fmaxf(mm, red[i]);
    red[0] = mm;
  }
  __syncthreads();
  float M = red[0];
  float e = __expf(v - M);
  float s = e;
  for (int off = 1; off < 64; off <<= 1) s += __shfl_xor(s, off, 64);
  if (lane == 0) red2[wid] = s;
  __syncthreads();
  if (tid == 0) {
    float ss = 0.f;
    for (int i = 0; i < 8; ++i) ss += red2[i];
    red2[0] = ss;
  }
  __syncthreads();
  alpha[b * NS + tid] = e / red2[0];
}

// ---------- v_ts partials: pure stream of alpha + mp ----------
__global__ __launch_bounds__(192) void k_vts(const unsigned short* __restrict__ mp,
                                             const float* __restrict__ alpha,
                                             float* __restrict__ part_vts) {
  int sc = blockIdx.x, b = blockIdx.y, tid = threadIdx.x;
  __shared__ float al[32];
  if (tid < 32) al[tid] = alpha[b * NS + sc * 32 + tid];
  __syncthreads();
  int d0 = tid * 4;
  float a0 = 0, a1 = 0, a2 = 0, a3 = 0;
#pragma unroll 8
  for (int s = 0; s < 32; ++s) {
    size_t row = (size_t)b * NS + sc * 32 + s;
    uint2 pk = *(const uint2*)(mp + row * ND + d0);
    float a = al[s];
    a0 += a * __uint_as_float(pk.x << 16);
    a1 += a * __uint_as_float(pk.x & 0xFFFF0000u);
    a2 += a * __uint_as_float(pk.y << 16);
    a3 += a * __uint_as_float(pk.y & 0xFFFF0000u);
  }
  float4 o; o.x = a0; o.y = a1; o.z = a2; o.w = a3;
  *(float4*)(part_vts + ((size_t)sc * NB + b) * ND + d0) = o;
}

// ---------- u_part[dc] = partial( (v_ts+v_s) @ Wm ) ----------
// b-FASTEST (64,6,4); v_ts folded from 16 partials (L2-resident); plain store.
__global__ __launch_bounds__(128) void k_final1(const float* __restrict__ part_vts,
                                                const float* __restrict__ v_s,
                                                const float* __restrict__ Wm,
                                                float* __restrict__ u_part) {
  int b = blockIdx.x, et = blockIdx.y, dc = blockIdx.z, tid = threadIdx.x;
  __shared__ float vbuf[192];
  for (int j = tid; j < 192; j += 128) {
    int d = dc * 192 + j;
    float v = v_s[b * ND + d];
#pragma unroll
    for (int p = 0; p < 16; ++p) v += part_vts[((size_t)p * NB + b) * ND + d];
    vbuf[j] = v;
  }
  __syncthreads();
  int e = et * 128 + tid;
  float acc = 0.f;
  const float* Wk = Wm + (size_t)(dc * 192) * ND + e;
#pragma unroll 8
  for (int j = 0; j < 192; ++j) acc += vbuf[j] * Wk[(size_t)j * ND];
  u_part[((size_t)dc * NB + b) * ND + e] = acc;
}

// ---------- logits = tanh(sum u_part + bm) @ Wd + bd ----------
__global__ __launch_bounds__(256) void k_final2(const float* __restrict__ u_part,
                                                const float* __restrict__ bm,
                                                const float* __restrict__ Wd,
                                                const float* __restrict__ bd,
                                                float* __restrict__ out) {
  int b = blockIdx.x, tid = threadIdx.x;
  int wid = tid >> 6, lane = tid & 63;
  __shared__ float red[4][3];
  float p0 = 0, p1 = 0, p2 = 0;
  for (int e = tid; e < ND; e += 256) {
    float uv = bm[e];
#pragma unroll
    for (int dc = 0; dc < 4; ++dc) uv += u_part[((size_t)dc * NB + b) * ND + e];
    float vm = fast_tanh(uv);
    p0 += vm * Wd[e * 3 + 0];
    p1 += vm * Wd[e * 3 + 1];
    p2 += vm * Wd[e * 3 + 2];
  }
  for (int off = 1; off < 64; off <<= 1) {
    p0 += __shfl_xor(p0, off, 64);
    p1 += __shfl_xor(p1, off, 64);
    p2 += __shfl_xor(p2, off, 64);
  }
  if (lane == 0) { red[wid][0] = p0; red[wid][1] = p1; red[wid][2] = p2; }
  __syncthreads();
  if (tid == 0) {
    out[b * 3 + 0] = red[0][0] + red[1][0] + red[2][0] + red[3][0] + bd[0];
    out[b * 3 + 1] = red[0][1] + red[1][1] + red[2][1] + red[3][1] + bd[1];
    out[b * 3 + 2] = red[0][2] + red[1][2] + red[2][2] + red[3][2] + bd[2];
  }
}

extern "C" void kernel_launch(void* const* d_in, const int* in_sizes, int n_in,
                              void* d_out, int out_size, void* d_ws, size_t ws_size,
                              hipStream_t stream) {
  const float* memory = (const float*)d_in[0];
  const float* aspect = (const float*)d_in[1];
  const int* ids = (const int*)d_in[2];
  const int* tids = (const int*)d_in[3];
  const float* W1 = (const float*)d_in[4];
  const float* b1 = (const float*)d_in[5];
  const float* w2 = (const float*)d_in[6];
  const float* Wm = (const float*)d_in[7];
  const float* bm = (const float*)d_in[8];
  const float* Wd = (const float*)d_in[9];
  const float* bd = (const float*)d_in[10];
  float* out = (float*)d_out;

  char* ws = (char*)d_ws;
  float* part_vs = (float*)(ws + OFF_PVS);
  float* part_vts = (float*)(ws + OFF_PVTS);
  float* ctx_part = (float*)(ws + OFF_PCTX);
  float* ctx = (float*)(ws + OFF_CTX);
  float* u_part = (float*)(ws + OFF_PU);
  float* sc_part = (float*)(ws + OFF_PSC);
  float* alpha = (float*)(ws + OFF_ALPHA);
  float* v_s = (float*)(ws + OFF_VS);
  float* v_a = (float*)(ws + OFF_VA);
  float* lens = (float*)(ws + OFF_LENS);
  unsigned short* w1mt = (unsigned short*)(ws + OFF_W1MT);
  unsigned short* mp = (unsigned short*)(ws + OFF_MP);

  // no memset: every workspace buffer is fully written before it is read.

  k_prep_tr<<<640, 256, 0, stream>>>(ids, tids, aspect, W1, v_a, lens, w1mt);
  k_vs_mprime<<<dim3(32, NB), 192, 0, stream>>>(memory, lens, part_vs, mp);
  k_reduce_vs<<<NB, 192, 0, stream>>>(part_vs, v_s);
  k_ctx<<<dim3(64, 6, 4), 128, 0, stream>>>(W1, v_a, v_s, ctx_part);
  k_reduce_ctx<<<NB, 192, 0, stream>>>(ctx_part, b1, ctx);
  k_gemm_scores<<<1536, 256, 0, stream>>>(mp, w1mt, ctx, w2, sc_part);
  k_softmax<<<NB, 512, 0, stream>>>(sc_part, alpha);
  k_vts<<<dim3(16, NB), 192, 0, stream>>>(mp, alpha, part_vts);
  k_final1<<<dim3(64, 6, 4), 128, 0, stream>>>(part_vts, v_s, Wm, u_part);
  k_final2<<<NB, 256, 0, stream>>>(u_part, bm, Wd, bd, out);
}